// Round 8
// baseline (245.008 us; speedup 1.0000x reference)
//
#include <hip/hip_runtime.h>

#define F 256
#define TWO_F 512

typedef __attribute__((ext_vector_type(8))) short short8;
typedef __attribute__((ext_vector_type(4))) float float4v;

// ---------- bf16 helpers ----------
static __device__ __forceinline__ unsigned short f2bf(float f) {
    unsigned u = __float_as_uint(f);
    u += 0x7FFFu + ((u >> 16) & 1u);
    return (unsigned short)(u >> 16);
}
// pack two floats -> two bf16 (round-half-up) in 2 adds + 1 v_perm
static __device__ __forceinline__ unsigned pack2(float lo, float hi) {
    unsigned a = __float_as_uint(lo) + 0x8000u;
    unsigned b = __float_as_uint(hi) + 0x8000u;
    return __builtin_amdgcn_perm(b, a, 0x07060302u);
}
static __device__ __forceinline__ float blo(unsigned u) { return __uint_as_float(u << 16); }
static __device__ __forceinline__ float rawf(unsigned u) { return __uint_as_float(u); }

// ---------- kernel 1 (merged prep): h fp32->hb bf16 and W1 fp32->Wb bf16, both k-rotated ----------
// rotation: within each 64-elem k-block, elem k -> (k + (row&7)*8) & 63  (row = m for hb, n for Wb)
__global__ __launch_bounds__(256) void prep_kernel(
    const float* __restrict__ h, const float* __restrict__ W1,
    unsigned short* __restrict__ hb, unsigned short* __restrict__ Wb, int M)
{
    int i = blockIdx.x * blockDim.x + threadIdx.x;
    if (i < M * 128) {                       // h part: one bf16 pair per thread
        int m = i >> 7;
        int kp = (i & 127) * 2;
        float2 v = *(const float2*)(h + (size_t)m * F + kp);
        unsigned pk = pack2(v.x, v.y);
        int ksw = ((kp & 63) + (m & 7) * 8) & 63;   // rotation multiple of 8 -> pair intact
        *(unsigned*)(hb + (size_t)m * F + (kp & ~63) + ksw) = pk;
    }
    if (i < TWO_F * F) {                     // W part: one elem per thread
        int n = i >> 8;
        int k = i & 255;
        float v = W1[(n & 255) * TWO_F + ((n >> 8) << 8) + k];
        int kin_sw = ((k & 63) + (n & 7) * 8) & 63;
        Wb[n * F + (k & ~63) + kin_sw] = f2bf(v);
    }
}

// ---------- kernel 2: full-K single-barrier GEMM. BM=64, BN=64, BK=256. ----------
// C[m][n] = sum_k hb[m][k]*Wb[n][k] (+b1 for n<256), bf16 out. One __syncthreads per block.
__global__ __launch_bounds__(256, 2) void gemm_kernel(
    const unsigned short* __restrict__ hb, const unsigned short* __restrict__ Wb,
    const float* __restrict__ b1v, unsigned short* __restrict__ C, int M)
{
    __shared__ unsigned short sA[64 * F];   // 32 KB, row stride 512 B
    __shared__ unsigned short sB[64 * F];   // 32 KB

    // XCD pairing: ib = (m%8) + 8*n + 64*(m/8) -> all 8 n-blocks of one m-chunk share ib&7
    // (same XCD under round-robin), dispatched 8 apart -> 32 KB h-strip L2-reused 8x.
    const int ib = blockIdx.x;
    const int r8 = ib & 7;
    const int nb = (ib >> 3) & 7;
    const int mq = ib >> 6;
    const int mchunk = mq * 8 + r8;
    const int bm = mchunk * 64;
    if (bm >= M) return;
    const int bn = nb * 64;

    const int tid  = threadIdx.x;
    const int lane = tid & 63;
    const int wid  = tid >> 6;
    const int wm   = wid >> 1;          // 2x2 wave grid, wave tile 32x32
    const int wn   = wid & 1;
    const int quad = lane >> 4;
    const int l15  = lane & 15;
    const int rot  = (l15 & 7) * 8;

    // --- stage everything: one issue = 64 lanes x 16 B = 1024 B = 2 full rows ---
    #pragma unroll
    for (int p = 0; p < 8; ++p) {
        int idx = wid * 8 + p;               // 0..31 -> rows 2*idx, 2*idx+1
        int am = bm + 2 * idx; if (am > M - 2) am = M - 2;   // even clamp; bad rows discarded
        const unsigned short* ga = hb + (size_t)am * F + lane * 8;
        __builtin_amdgcn_global_load_lds(
            (const __attribute__((address_space(1))) unsigned int*)ga,
            (__attribute__((address_space(3))) unsigned int*)&sA[(2 * idx) * F],
            16, 0, 0);
        const unsigned short* gb = Wb + (size_t)(bn + 2 * idx) * F + lane * 8;
        __builtin_amdgcn_global_load_lds(
            (const __attribute__((address_space(1))) unsigned int*)gb,
            (__attribute__((address_space(3))) unsigned int*)&sB[(2 * idx) * F],
            16, 0, 0);
    }
    __syncthreads();   // the ONLY barrier

    float4v acc[2][2];
    acc[0][0] = acc[0][1] = acc[1][0] = acc[1][1] = (float4v)(0.f);

    #pragma unroll
    for (int ks = 0; ks < 8; ++ks) {
        // k offset with per-row 64-block rotation un-applied (row&7 == l15&7 since bm,bn % 8 == 0)
        const int off = ((ks >> 1) << 6) + ((((ks & 1) << 5) + (quad << 3) + rot) & 63);
        short8 afr[2], bfr[2];
        #pragma unroll
        for (int mt = 0; mt < 2; ++mt)
            afr[mt] = *(const short8*)&sA[(wm * 32 + mt * 16 + l15) * F + off];
        #pragma unroll
        for (int nt = 0; nt < 2; ++nt)
            bfr[nt] = *(const short8*)&sB[(wn * 32 + nt * 16 + l15) * F + off];
        #pragma unroll
        for (int mt = 0; mt < 2; ++mt)
            #pragma unroll
            for (int nt = 0; nt < 2; ++nt)
                acc[mt][nt] = __builtin_amdgcn_mfma_f32_16x16x32_bf16(
                    afr[mt], bfr[nt], acc[mt][nt], 0, 0, 0);
    }

    // epilogue: +b1 for the n<256 half, bf16 store
    float bias[2];
    #pragma unroll
    for (int nt = 0; nt < 2; ++nt) {
        int n = bn + wn * 32 + nt * 16 + l15;
        bias[nt] = (n < F) ? b1v[n] : 0.f;
    }
    #pragma unroll
    for (int mt = 0; mt < 2; ++mt) {
        int gm0 = bm + wm * 32 + mt * 16 + quad * 4;
        #pragma unroll
        for (int rr = 0; rr < 4; ++rr) {
            int gm = gm0 + rr;
            if (gm < M) {
                unsigned short* cp = C + (size_t)gm * TWO_F + bn + wn * 32 + l15;
                #pragma unroll
                for (int nt = 0; nt < 2; ++nt)
                    cp[nt * 16] = f2bf(acc[mt][nt][rr] + bias[nt]);
            }
        }
    }
}

// ---------- kernel 3: per-edge score, 2 edges per 32-lane group (measured-best, frozen) ----------
__global__ __launch_bounds__(256) void edge_kernel(
    const unsigned short* __restrict__ C,
    const int* __restrict__ src, const int* __restrict__ dst,
    const float* __restrict__ w2,
    const float* __restrict__ b2, float* __restrict__ out, int E)
{
    const int lane = threadIdx.x & 31;
    const int g = blockIdx.x * 8 + (threadIdx.x >> 5);
    const int e0 = g * 2;
    if (e0 >= E) return;
    const int s0 = src[e0], d0 = dst[e0];
    const int s1 = src[e0 + 1], d1 = dst[e0 + 1];

    uint4 av0 = *(const uint4*)(C + (size_t)s0 * TWO_F + lane * 8);
    uint4 bv0 = *(const uint4*)(C + (size_t)d0 * TWO_F + F + lane * 8);
    uint4 av1 = *(const uint4*)(C + (size_t)s1 * TWO_F + lane * 8);
    uint4 bv1 = *(const uint4*)(C + (size_t)d1 * TWO_F + F + lane * 8);
    float4 w0 = *(const float4*)(w2 + lane * 8);
    float4 w1 = *(const float4*)(w2 + lane * 8 + 4);

    float sum0, sum1;
    sum0  = w0.x * fmaxf(blo(av0.x) + blo(bv0.x), 0.f);
    sum0 += w0.y * fmaxf(rawf(av0.x) + rawf(bv0.x), 0.f);
    sum0 += w0.z * fmaxf(blo(av0.y) + blo(bv0.y), 0.f);
    sum0 += w0.w * fmaxf(rawf(av0.y) + rawf(bv0.y), 0.f);
    sum0 += w1.x * fmaxf(blo(av0.z) + blo(bv0.z), 0.f);
    sum0 += w1.y * fmaxf(rawf(av0.z) + rawf(bv0.z), 0.f);
    sum0 += w1.z * fmaxf(blo(av0.w) + blo(bv0.w), 0.f);
    sum0 += w1.w * fmaxf(rawf(av0.w) + rawf(bv0.w), 0.f);

    sum1  = w0.x * fmaxf(blo(av1.x) + blo(bv1.x), 0.f);
    sum1 += w0.y * fmaxf(rawf(av1.x) + rawf(bv1.x), 0.f);
    sum1 += w0.z * fmaxf(blo(av1.y) + blo(bv1.y), 0.f);
    sum1 += w0.w * fmaxf(rawf(av1.y) + rawf(bv1.y), 0.f);
    sum1 += w1.x * fmaxf(blo(av1.z) + blo(bv1.z), 0.f);
    sum1 += w1.y * fmaxf(rawf(av1.z) + rawf(bv1.z), 0.f);
    sum1 += w1.z * fmaxf(blo(av1.w) + blo(bv1.w), 0.f);
    sum1 += w1.w * fmaxf(rawf(av1.w) + rawf(bv1.w), 0.f);

    #pragma unroll
    for (int off = 16; off > 0; off >>= 1) {
        sum0 += __shfl_down(sum0, off, 32);
        sum1 += __shfl_down(sum1, off, 32);
    }

    if (lane == 0) {
        float b = b2[0];
        out[e0]     = sum0 + b;
        out[e0 + 1] = sum1 + b;
    }
}

extern "C" void kernel_launch(void* const* d_in, const int* in_sizes, int n_in,
                              void* d_out, int out_size, void* d_ws, size_t ws_size,
                              hipStream_t stream) {
    const float* h    = (const float*)d_in[0];
    const int*   src  = (const int*)d_in[1];
    const int*   dst  = (const int*)d_in[2];
    const float* W1_w = (const float*)d_in[3];
    const float* W1_b = (const float*)d_in[4];
    const float* W2_w = (const float*)d_in[5];
    const float* W2_b = (const float*)d_in[6];
    float* out = (float*)d_out;

    const int M = in_sizes[0] / F;   // 50000
    const int E = in_sizes[1];       // 800000

    // ws: [Wb bf16 256KB][pad to 512KB][hb bf16 25.6MB, pad to 26MB][C bf16 51.2MB]
    unsigned short* Wb = (unsigned short*)d_ws;
    unsigned short* hb = (unsigned short*)((char*)d_ws + 512 * 1024);
    unsigned short* C  = (unsigned short*)((char*)d_ws + 512 * 1024 + 26 * 1024 * 1024);

    int prep_threads = M * 128 > TWO_F * F ? M * 128 : TWO_F * F;
    prep_kernel<<<(prep_threads + 255) / 256, 256, 0, stream>>>(h, W1_w, hb, Wb, M);

    // grid: m-chunks of 64 rows (782 -> padded 784) x 8 n-blocks, XCD-paired encoding
    int mq = (((M + 63) / 64) + 7) / 8;            // 98
    gemm_kernel<<<mq * 64, 256, 0, stream>>>(hb, Wb, W1_b, C, M);

    edge_kernel<<<(E / 2 + 7) / 8, 256, 0, stream>>>(C, src, dst, W2_w, W2_b, out, E);
}